// Round 5
// baseline (163.650 us; speedup 1.0000x reference)
//
#include <hip/hip_runtime.h>

typedef unsigned short u16;
typedef __attribute__((ext_vector_type(8))) short bf16x8;   // MFMA A/B frag
typedef __attribute__((ext_vector_type(4))) float f32x4;    // MFMA C/D frag

#define BLOCK 256
#define TPB   2           // tiles per block (2 waves per tile: edge-split)

__device__ __forceinline__ u16 f2bf(float f) {   // RNE f32 -> bf16
    union { float f; unsigned u; } v; v.f = f;
    unsigned r = v.u + 0x7fff + ((v.u >> 16) & 1);
    return (u16)(r >> 16);
}

// One tile = 16 outputs; TWO waves per tile, each covering 8 of the 16 edges
// over the full k-range, partial C summed via LDS.
//   A1: lane (m=lane&15, quad) computes edges t = {quad, 4+quad} (+eh*8) -> sph,idx
//   A2: per c-half h: acc[s][j] += sph_t[s]*feat[idx_t][h*32+quad*8+j] over 8 t
//   B : C[nt] += afr[s] x KB[nt][2s+h]   (mfma_f32_16x16x32_bf16)
//   Red: eh=1 wave writes C to LDS; eh=0 wave sums, adds bias, stores.
__global__ __launch_bounds__(BLOCK, 4)
void sphconv_split(const float* __restrict__ feats,    // [N_IN, 64]
                   const float* __restrict__ in_pos,   // [N_IN, 3]
                   const float* __restrict__ out_pos,  // [N_OUT, 3]
                   const float* __restrict__ extents,  // [1]
                   const float* __restrict__ kmat,     // [4,64,64] = [k=256][n=64]
                   const float* __restrict__ bias,     // [64]
                   const int* __restrict__ nidx,       // [E]
                   const int* __restrict__ rsplits,    // [N_OUT+1]
                   float* __restrict__ out,            // [N_OUT,64]
                   int n_out, int ntiles, int n_edges)
{
    __shared__ u16 KB[16384];                       // 32 KB: [nt][ks][lane][j] B-frags
    __shared__ __align__(16) float red[TPB][4][64][4];  // 8 KB: partial C

    const int tid = threadIdx.x, wave = tid >> 6, lane = tid & 63;

    // ---- stage K as bf16 MFMA B-fragments (broadcast read, L2-resident) ----
    for (int i = tid; i < 16384; i += BLOCK) {
        const int k = i >> 6, n = i & 63;           // kmat flat = [k][n]
        const int nt = n >> 4, ks = k >> 5;
        const int lanep = (((k >> 3) & 3) << 4) | (n & 15), j = k & 7;
        KB[(((((nt << 3) | ks) << 6) | lanep) << 3) | j] = f2bf(kmat[i]);
    }

    const int tslot = wave >> 1;                    // tile within block
    const int eh    = wave & 1;                     // which 8-edge half
    const int tile  = blockIdx.x * TPB + tslot;
    const int tile_c = min(tile, ntiles - 1);       // clamp: no divergence at barriers
    const int m = lane & 15, quad = lane >> 4;
    const int obase = tile_c << 4;
    const int o  = obase + m;
    const int oc = min(o, n_out - 1);
    const int e0 = rsplits[oc];
    const int e1 = rsplits[oc + 1];
    const float qx = out_pos[oc * 3 + 0];
    const float qy = out_pos[oc * 3 + 1];
    const float qz = out_pos[oc * 3 + 2];
    const float inv_ext = __fdividef(1.f, extents[0]);

    // ---- A1: this wave's 8 edges spread over lanes (t = u*4 + quad) ----
    float sph_r[2][4]; int idx_r[2];
    #pragma unroll
    for (int u = 0; u < 2; ++u) {
        const int t = (u << 2) | quad;
        const int e = e0 + (eh << 3) + t;
        const bool v = (o < n_out) && (e < e1);
        const int id = nidx[min(e, n_edges - 1)];
        const float dx = in_pos[id * 3 + 0] - qx;
        const float dy = in_pos[id * 3 + 1] - qy;
        const float dz = in_pos[id * 3 + 2] - qz;
        const float rp2 = dx * dx + dy * dy;
        const float r2  = rp2 + dz * dz;
        const float rs  = fmaxf(sqrtf(r2), 1e-10f);
        const float rp  = fmaxf(sqrtf(rp2), 1e-10f);
        const float ir  = __fdividef(1.f, rs);
        const float irp = __fdividef(1.f, rp);
        sph_r[u][0] = v ? rs * inv_ext : 0.f;
        sph_r[u][1] = v ? dz * ir      : 0.f;
        sph_r[u][2] = v ? dy * irp     : 0.f;
        sph_r[u][3] = v ? dx * irp     : 0.f;
        idx_r[u] = id;          // row gathered harmlessly when weights are 0
    }

    // pre-shuffle the 8 edge indices (gather addresses dep-free in the loop)
    int idx_sh[8];
    #pragma unroll
    for (int t = 0; t < 8; ++t)
        idx_sh[t] = __shfl(idx_r[t >> 2], ((t & 3) << 4) | m, 64);

    __syncthreads();            // KB staged (placed late to overlap with A1 latency)

    f32x4 C[4] = {{0,0,0,0},{0,0,0,0},{0,0,0,0},{0,0,0,0}};
    const bf16x8* kbp = (const bf16x8*)KB;

    #pragma unroll
    for (int h = 0; h < 2; ++h) {              // c-half: c = h*32 + quad*8 + j
        float acc[4][8];
        #pragma unroll
        for (int s = 0; s < 4; ++s)
            #pragma unroll
            for (int j = 0; j < 8; ++j) acc[s][j] = 0.f;

        #pragma unroll
        for (int t = 0; t < 8; ++t) {
            const float* fp = feats + (idx_sh[t] << 6) + (h << 5) + (quad << 3);
            const float4 A0 = *(const float4*)fp;
            const float4 A1 = *(const float4*)(fp + 4);
            const int src = ((t & 3) << 4) | m;
            const float s0 = __shfl(sph_r[t >> 2][0], src, 64);
            const float s1 = __shfl(sph_r[t >> 2][1], src, 64);
            const float s2 = __shfl(sph_r[t >> 2][2], src, 64);
            const float s3 = __shfl(sph_r[t >> 2][3], src, 64);
            const float fv[8] = {A0.x, A0.y, A0.z, A0.w, A1.x, A1.y, A1.z, A1.w};
            #pragma unroll
            for (int j = 0; j < 8; ++j) {
                acc[0][j] = fmaf(s0, fv[j], acc[0][j]);
                acc[1][j] = fmaf(s1, fv[j], acc[1][j]);
                acc[2][j] = fmaf(s2, fv[j], acc[2][j]);
                acc[3][j] = fmaf(s3, fv[j], acc[3][j]);
            }
        }

        bf16x8 afr[4];
        #pragma unroll
        for (int s = 0; s < 4; ++s) {
            union { u16 hh[8]; bf16x8 v; } p;
            #pragma unroll
            for (int j = 0; j < 8; ++j) p.hh[j] = f2bf(acc[s][j]);
            afr[s] = p.v;
        }

        #pragma unroll
        for (int nt = 0; nt < 4; ++nt)
            #pragma unroll
            for (int s = 0; s < 4; ++s) {
                const bf16x8 b = kbp[(((nt << 3) | ((s << 1) | h)) << 6) | lane];
                C[nt] = __builtin_amdgcn_mfma_f32_16x16x32_bf16(afr[s], b, C[nt], 0, 0, 0);
            }
    }

    // ---- pair reduction + epilogue ----
    if (eh == 1) {
        #pragma unroll
        for (int nt = 0; nt < 4; ++nt)
            *(f32x4*)&red[tslot][nt][lane][0] = C[nt];   // ds_write_b128, dense
    }
    __syncthreads();
    if (eh == 0 && tile < ntiles) {
        #pragma unroll
        for (int nt = 0; nt < 4; ++nt) {
            const f32x4 P = *(const f32x4*)&red[tslot][nt][lane][0];
            const int f = (nt << 4) | m;                 // D: n = lane&15
            const float bv = bias[f];
            #pragma unroll
            for (int r = 0; r < 4; ++r) {
                const int oo = obase + (quad << 2) + r;  // D: m = quad*4 + r
                if (oo < n_out) out[(oo << 6) | f] = C[nt][r] + P[r] + bv;
            }
        }
    }
}

extern "C" void kernel_launch(void* const* d_in, const int* in_sizes, int n_in,
                              void* d_out, int out_size, void* d_ws, size_t ws_size,
                              hipStream_t stream) {
    const float* feats   = (const float*)d_in[0];
    const float* in_pos  = (const float*)d_in[1];
    const float* out_pos = (const float*)d_in[2];
    const float* extents = (const float*)d_in[3];
    const float* kmat    = (const float*)d_in[4];
    const float* bias    = (const float*)d_in[5];
    const int*   nidx    = (const int*)d_in[6];
    const int*   rsplits = (const int*)d_in[7];
    const int n_out   = in_sizes[7] - 1;
    const int n_edges = in_sizes[6];
    const int ntiles  = (n_out + 15) >> 4;
    const int grid    = (ntiles + TPB - 1) / TPB;

    sphconv_split<<<grid, BLOCK, 0, stream>>>(
        feats, in_pos, out_pos, extents, kmat, bias, nidx, rsplits,
        (float*)d_out, n_out, ntiles, n_edges);
}

// Round 6
// 159.992 us; speedup vs baseline: 1.0229x; 1.0229x over previous
//
#include <hip/hip_runtime.h>

typedef unsigned short u16;
typedef __attribute__((ext_vector_type(8))) short bf16x8;   // MFMA A/B frag: 8 bf16
typedef __attribute__((ext_vector_type(4))) float f32x4;    // MFMA C/D frag

#define WPB   4              // waves per block; one 16-output tile per wave
#define BLOCK (WPB * 64)

__device__ __forceinline__ u16 f2bf(float f) {   // RNE f32 -> bf16
    union { float f; unsigned u; } v; v.f = f;
    unsigned r = v.u + 0x7fff + ((v.u >> 16) & 1);
    return (u16)(r >> 16);
}

// One wave handles 16 outputs (one MFMA M-tile):
//   A1: 256 edges spread over lanes (4/lane) -> sph[4] + idx staged in LDS
//   A2: lane(m=lane&15, quad=lane>>4) accumulates acc[kstep][j] (A-frag layout)
//       idx for all 16 edges hoisted to registers first (R6: removes the
//       in-loop LDS dependency from the gather address chain; full unroll
//       lets the compiler keep the 64 independent 16B loads in flight)
//   B : 4 n-tiles x 8 k-steps of mfma_f32_16x16x32_bf16 against LDS-staged
//       K B-fragments;  out[o][f] = D + bias[f]
__global__ __launch_bounds__(BLOCK, 3)
void sphconv_mfma(const float* __restrict__ feats,    // [N_IN, 64]
                  const float* __restrict__ in_pos,   // [N_IN, 3]
                  const float* __restrict__ out_pos,  // [N_OUT, 3]
                  const float* __restrict__ extents,  // [1]
                  const float* __restrict__ kmat,     // [4,64,64] = [k=256][f=64]
                  const float* __restrict__ bias,     // [64]
                  const int* __restrict__ nidx,       // [E]
                  const int* __restrict__ rsplits,    // [N_OUT+1]
                  float* __restrict__ out,            // [N_OUT,64]
                  int n_out, int ntiles)
{
    // K as ready-made B-fragments, bf16: [ntile][kstep][lane][j]  (32 KB)
    __shared__ u16 KB[4 * 8 * 64 * 8];
    // wave-private tile scratch
    __shared__ int   idxL[WPB][16][16];      // [wave][t][m]       (4 KB)
    __shared__ float sphL[WPB][16][16][4];   // [wave][t][m][s]    (16 KB)

    const int tid  = threadIdx.x;
    const int wave = tid >> 6;
    const int lane = tid & 63;

    // ---- stage K (coalesced global read, scattered LDS u16 write; once) ----
    for (int i = tid; i < 16384; i += BLOCK) {
        const int n = i & 63, k = i >> 6;               // kmat flat = [k][n]
        const int kstep = k >> 5, quad = (k >> 3) & 3, j = k & 7;
        const int ntile = n >> 4, lanep = (quad << 4) | (n & 15);
        KB[((((ntile << 3) | kstep) << 6) | lanep) * 8 + j] = f2bf(kmat[i]);
    }
    __syncthreads();   // the only block-wide barrier

    const int tile = blockIdx.x * WPB + wave;
    if (tile >= ntiles) return;

    const float inv_ext = __fdividef(1.0f, extents[0]);

    // ---------------- Phase A1: per-edge spherical basis (4 edges/lane) ----------------
    #pragma unroll
    for (int u = 0; u < 4; ++u) {
        const int slot = (u << 6) | lane;      // 0..255 within tile
        const int m = slot >> 4, t = slot & 15;
        const int o = (tile << 4) | m;
        float rn = 0.f, cph = 0.f, sth = 0.f, cth = 0.f;
        int idx = 0;
        if (o < n_out) {
            const int e0 = rsplits[o], e1 = rsplits[o + 1];
            const int e = e0 + t;
            if (e < e1) {
                idx = nidx[e];
                const float dx = in_pos[idx * 3 + 0] - out_pos[o * 3 + 0];
                const float dy = in_pos[idx * 3 + 1] - out_pos[o * 3 + 1];
                const float dz = in_pos[idx * 3 + 2] - out_pos[o * 3 + 2];
                const float rp2 = dx * dx + dy * dy;
                const float r2  = rp2 + dz * dz;
                const float rs  = fmaxf(sqrtf(r2), 1e-10f);
                const float rp  = fmaxf(sqrtf(rp2), 1e-10f);
                const float ir  = __fdividef(1.0f, rs);
                const float irp = __fdividef(1.0f, rp);
                rn  = rs * inv_ext;
                cph = dz * ir;
                sth = dy * irp;
                cth = dx * irp;
            }
        }
        idxL[wave][t][m] = idx;
        f32x4 sv; sv.x = rn; sv.y = cph; sv.z = sth; sv.w = cth;
        *(f32x4*)&sphL[wave][t][m][0] = sv;     // ds_write_b128
    }
    __builtin_amdgcn_wave_barrier();   // order A1 LDS writes vs A2 cross-lane reads

    // ---------------- Phase A2: accumulate A-fragments in registers ----------------
    const int m    = lane & 15;
    const int quad = lane >> 4;
    float acc[8][8];
    #pragma unroll
    for (int ks = 0; ks < 8; ++ks)
        #pragma unroll
        for (int j = 0; j < 8; ++j) acc[ks][j] = 0.f;

    // R6: hoist all 16 edge indices out of the loop (dep-free gather addresses)
    int idx_r[16];
    #pragma unroll
    for (int t = 0; t < 16; ++t) idx_r[t] = idxL[wave][t][m];

    #pragma unroll
    for (int t = 0; t < 16; ++t) {
        const f32x4 sv  = *(const f32x4*)&sphL[wave][t][m][0];
        const float* fr = feats + (idx_r[t] << 6) + (quad << 3);
        const float4 lo0 = *(const float4*)(fr +  0);
        const float4 lo1 = *(const float4*)(fr +  4);
        const float4 hi0 = *(const float4*)(fr + 32);
        const float4 hi1 = *(const float4*)(fr + 36);
        #pragma unroll
        for (int s = 0; s < 4; ++s) {
            const float w = sv[s];
            float* aL = acc[2 * s];          // c = quad*8 + j
            float* aH = acc[2 * s + 1];      // c = 32 + quad*8 + j
            aL[0] = fmaf(w, lo0.x, aL[0]); aL[1] = fmaf(w, lo0.y, aL[1]);
            aL[2] = fmaf(w, lo0.z, aL[2]); aL[3] = fmaf(w, lo0.w, aL[3]);
            aL[4] = fmaf(w, lo1.x, aL[4]); aL[5] = fmaf(w, lo1.y, aL[5]);
            aL[6] = fmaf(w, lo1.z, aL[6]); aL[7] = fmaf(w, lo1.w, aL[7]);
            aH[0] = fmaf(w, hi0.x, aH[0]); aH[1] = fmaf(w, hi0.y, aH[1]);
            aH[2] = fmaf(w, hi0.z, aH[2]); aH[3] = fmaf(w, hi0.w, aH[3]);
            aH[4] = fmaf(w, hi1.x, aH[4]); aH[5] = fmaf(w, hi1.y, aH[5]);
            aH[6] = fmaf(w, hi1.z, aH[6]); aH[7] = fmaf(w, hi1.w, aH[7]);
        }
    }

    // ---- pack acc -> bf16 A-fragments ----
    bf16x8 afr[8];
    #pragma unroll
    for (int ks = 0; ks < 8; ++ks) {
        union { u16 h[8]; bf16x8 v; } p;
        #pragma unroll
        for (int j = 0; j < 8; ++j) p.h[j] = f2bf(acc[ks][j]);
        afr[ks] = p.v;
    }

    // ---------------- Phase B: 4 n-tiles x 8 k-steps of MFMA ----------------
    const int obase = tile << 4;
    #pragma unroll
    for (int nt = 0; nt < 4; ++nt) {
        f32x4 C = {0.f, 0.f, 0.f, 0.f};
        const u16* kb = &KB[((nt << 3) << 6) * 8 + lane * 8];
        #pragma unroll
        for (int ks = 0; ks < 8; ++ks) {
            const bf16x8 b = *(const bf16x8*)(kb + (ks << 6) * 8);  // ds_read_b128
            C = __builtin_amdgcn_mfma_f32_16x16x32_bf16(afr[ks], b, C, 0, 0, 0);
        }
        const int f  = (nt << 4) | m;          // n = lane&15
        const float bv = bias[f];
        #pragma unroll
        for (int r = 0; r < 4; ++r) {
            const int oo = obase + (quad << 2) + r;   // m = quad*4 + reg
            if (oo < n_out) out[(oo << 6) | f] = C[r] + bv;
        }
    }
}

extern "C" void kernel_launch(void* const* d_in, const int* in_sizes, int n_in,
                              void* d_out, int out_size, void* d_ws, size_t ws_size,
                              hipStream_t stream) {
    const float* feats   = (const float*)d_in[0];
    const float* in_pos  = (const float*)d_in[1];
    const float* out_pos = (const float*)d_in[2];
    const float* extents = (const float*)d_in[3];
    const float* kmat    = (const float*)d_in[4];
    const float* bias    = (const float*)d_in[5];
    const int*   nidx    = (const int*)d_in[6];
    const int*   rsplits = (const int*)d_in[7];
    const int n_out  = in_sizes[7] - 1;
    const int ntiles = (n_out + 15) >> 4;
    const int grid   = (ntiles + WPB - 1) / WPB;

    sphconv_mfma<<<grid, BLOCK, 0, stream>>>(
        feats, in_pos, out_pos, extents, kmat, bias, nidx, rsplits,
        (float*)d_out, n_out, ntiles);
}

// Round 7
// 134.283 us; speedup vs baseline: 1.2187x; 1.1915x over previous
//
#include <hip/hip_runtime.h>

typedef unsigned short u16;
typedef __attribute__((ext_vector_type(8))) short bf16x8;   // MFMA A/B frag
typedef __attribute__((ext_vector_type(4))) float f32x4;    // MFMA C/D frag

#define BLOCK 256
#define TPB   2        // tiles per block; 2 waves per tile (edge-split t 0-7 / 8-15)

__device__ __forceinline__ u16 f2bf(float f) {   // RNE f32 -> bf16
    union { float f; unsigned u; } v; v.f = f;
    unsigned r = v.u + 0x7fff + ((v.u >> 16) & 1);
    return (u16)(r >> 16);
}

// One tile = 16 outputs. TWO waves per tile, each covering 8 of its 16 edges
// over the FULL k-range (identical inner body to the proven R3 kernel),
// partial C summed via an LDS buffer aliased over the A1 scratch.
//   A1: wave's 8 t-slots x 16 m spread over lanes (2/lane) -> f16 sph + idx, LDS
//   A2: lane(m=lane&15,quad) acc[ks][j] += sph_t[s]*feat[idx_t][c] over 8 t
//   B : 4 nt x 8 ks mfma_f32_16x16x32_bf16 vs LDS B-frags -> partial C
//   Red: h=1 wave writes C chunks; h=0 wave sums + bias + stores.
__global__ __launch_bounds__(BLOCK, 4)
void sphconv_esplit(const float* __restrict__ feats,    // [N_IN, 64]
                    const float* __restrict__ in_pos,   // [N_IN, 3]
                    const float* __restrict__ out_pos,  // [N_OUT, 3]
                    const float* __restrict__ extents,  // [1]
                    const float* __restrict__ kmat,     // [4,64,64] = [k=256][n=64]
                    const float* __restrict__ bias,     // [64]
                    const int* __restrict__ nidx,       // [E]
                    const int* __restrict__ rsplits,    // [N_OUT+1]
                    float* __restrict__ out,            // [N_OUT,64]
                    int n_out, int ntiles, int n_edges)
{
    __shared__ u16 KB[16384];                       // 32 KB: [nt][ks][lane][j] B-frags
    __shared__ __align__(16) unsigned char SCR[6144];  // per-wave A1 scratch / red alias

    const int tid = threadIdx.x, wave = tid >> 6, lane = tid & 63;

    // ---- stage K as bf16 MFMA B-fragments (as R3) ----
    for (int i = tid; i < 16384; i += BLOCK) {
        const int k = i >> 6, n = i & 63;           // kmat flat = [k][n]
        const int nt = n >> 4, ks = k >> 5;
        const int lanep = (((k >> 3) & 3) << 4) | (n & 15), j = k & 7;
        KB[(((((nt << 3) | ks) << 6) | lanep) << 3) | j] = f2bf(kmat[i]);
    }

    const int ts = wave >> 1;                       // tile slot in block
    const int h  = wave & 1;                        // edge half: t = h*8 + [0,8)
    const int tile = blockIdx.x * TPB + ts;
    const int tile_c = min(tile, ntiles - 1);       // clamp: keep barriers uniform
    const int m = lane & 15, quad = lane >> 4;
    const int obase = tile_c << 4;

    _Float16* sph_w = (_Float16*)(SCR + wave * 1536);        // [8][16][4] f16 (1 KB)
    int*      idx_w = (int*)     (SCR + wave * 1536 + 1024); // [8][16]    (512 B)

    const float inv_ext = __fdividef(1.f, extents[0]);

    // ---- A1: this wave's 128 (t,m) pairs, 2 per lane ----
    #pragma unroll
    for (int u = 0; u < 2; ++u) {
        const int slot = (u << 6) | lane;           // 0..127
        const int tl = slot >> 4, mm = slot & 15;
        const int o  = obase + mm;
        const int oc = min(o, n_out - 1);
        const int e0 = rsplits[oc], e1 = rsplits[oc + 1];
        const int e  = e0 + (h << 3) + tl;
        const bool v = (o < n_out) && (e < e1);
        const int id = nidx[min(e, n_edges - 1)];
        const float dx = in_pos[id * 3 + 0] - out_pos[oc * 3 + 0];
        const float dy = in_pos[id * 3 + 1] - out_pos[oc * 3 + 1];
        const float dz = in_pos[id * 3 + 2] - out_pos[oc * 3 + 2];
        const float rp2 = dx * dx + dy * dy;
        const float r2  = rp2 + dz * dz;
        const float rs  = fmaxf(sqrtf(r2), 1e-10f);
        const float rp  = fmaxf(sqrtf(rp2), 1e-10f);
        const float ir  = __fdividef(1.f, rs);
        const float irp = __fdividef(1.f, rp);
        union { _Float16 hh[4]; short4 s4; } pk;
        pk.hh[0] = (_Float16)(v ? rs * inv_ext : 0.f);
        pk.hh[1] = (_Float16)(v ? dz * ir      : 0.f);
        pk.hh[2] = (_Float16)(v ? dy * irp     : 0.f);
        pk.hh[3] = (_Float16)(v ? dx * irp     : 0.f);
        idx_w[(tl << 4) | mm] = id;
        *(short4*)&sph_w[((tl << 4) | mm) << 2] = pk.s4;   // 8B, m-contig: no conflict
    }
    __syncthreads();      // KB staged + A1 scratch visible

    // ---- A2: accumulate A-fragments (R3's proven inner body, 8 t) ----
    float acc[8][8];
    #pragma unroll
    for (int ks = 0; ks < 8; ++ks)
        #pragma unroll
        for (int j = 0; j < 8; ++j) acc[ks][j] = 0.f;

    #pragma unroll 4
    for (int tl = 0; tl < 8; ++tl) {
        const int idx = idx_w[(tl << 4) | m];
        union { short4 s4; _Float16 hh[4]; } up;
        up.s4 = *(const short4*)&sph_w[((tl << 4) | m) << 2];
        const float* fr = feats + (idx << 6) + (quad << 3);
        const float4 lo0 = *(const float4*)(fr +  0);
        const float4 lo1 = *(const float4*)(fr +  4);
        const float4 hi0 = *(const float4*)(fr + 32);
        const float4 hi1 = *(const float4*)(fr + 36);
        #pragma unroll
        for (int s = 0; s < 4; ++s) {
            const float w = (float)up.hh[s];
            float* aL = acc[2 * s];          // c = quad*8 + j
            float* aH = acc[2 * s + 1];      // c = 32 + quad*8 + j
            aL[0] = fmaf(w, lo0.x, aL[0]); aL[1] = fmaf(w, lo0.y, aL[1]);
            aL[2] = fmaf(w, lo0.z, aL[2]); aL[3] = fmaf(w, lo0.w, aL[3]);
            aL[4] = fmaf(w, lo1.x, aL[4]); aL[5] = fmaf(w, lo1.y, aL[5]);
            aL[6] = fmaf(w, lo1.z, aL[6]); aL[7] = fmaf(w, lo1.w, aL[7]);
            aH[0] = fmaf(w, hi0.x, aH[0]); aH[1] = fmaf(w, hi0.y, aH[1]);
            aH[2] = fmaf(w, hi0.z, aH[2]); aH[3] = fmaf(w, hi0.w, aH[3]);
            aH[4] = fmaf(w, hi1.x, aH[4]); aH[5] = fmaf(w, hi1.y, aH[5]);
            aH[6] = fmaf(w, hi1.z, aH[6]); aH[7] = fmaf(w, hi1.w, aH[7]);
        }
    }

    bf16x8 afr[8];
    #pragma unroll
    for (int ks = 0; ks < 8; ++ks) {
        union { u16 hh[8]; bf16x8 v; } p;
        #pragma unroll
        for (int j = 0; j < 8; ++j) p.hh[j] = f2bf(acc[ks][j]);
        afr[ks] = p.v;
    }

    // ---- B: 4 n-tiles x 8 k-steps MFMA (full k; partial over edges) ----
    f32x4 C[4] = {{0,0,0,0},{0,0,0,0},{0,0,0,0},{0,0,0,0}};
    const bf16x8* kbp = (const bf16x8*)KB;
    #pragma unroll
    for (int nt = 0; nt < 4; ++nt)
        #pragma unroll
        for (int ks = 0; ks < 8; ++ks) {
            const bf16x8 b = kbp[(((nt << 3) | ks) << 6) | lane];
            C[nt] = __builtin_amdgcn_mfma_f32_16x16x32_bf16(afr[ks], b, C[nt], 0, 0, 0);
        }

    // ---- pair reduction (chunked over nt pairs; red aliases A1 scratch) ----
    f32x4* redp = (f32x4*)SCR;                      // [ts][nt2][lane], 4 KB per chunk
    const bool store_ok = (tile < ntiles);
    __syncthreads();                                // A2 scratch reads done
    if (h == 1) {
        redp[((ts << 1) | 0) * 64 + lane] = C[0];
        redp[((ts << 1) | 1) * 64 + lane] = C[1];
    }
    __syncthreads();
    if (h == 0 && store_ok) {
        #pragma unroll
        for (int nt = 0; nt < 2; ++nt) {
            const f32x4 P = redp[((ts << 1) | nt) * 64 + lane];
            const int f = (nt << 4) | m;
            const float bv = bias[f];
            #pragma unroll
            for (int r = 0; r < 4; ++r) {
                const int oo = obase + (quad << 2) + r;
                if (oo < n_out) out[(oo << 6) | f] = C[nt][r] + P[r] + bv;
            }
        }
    }
    __syncthreads();
    if (h == 1) {
        redp[((ts << 1) | 0) * 64 + lane] = C[2];
        redp[((ts << 1) | 1) * 64 + lane] = C[3];
    }
    __syncthreads();
    if (h == 0 && store_ok) {
        #pragma unroll
        for (int nt = 2; nt < 4; ++nt) {
            const f32x4 P = redp[((ts << 1) | (nt - 2)) * 64 + lane];
            const int f = (nt << 4) | m;
            const float bv = bias[f];
            #pragma unroll
            for (int r = 0; r < 4; ++r) {
                const int oo = obase + (quad << 2) + r;
                if (oo < n_out) out[(oo << 6) | f] = C[nt][r] + P[r] + bv;
            }
        }
    }
}

extern "C" void kernel_launch(void* const* d_in, const int* in_sizes, int n_in,
                              void* d_out, int out_size, void* d_ws, size_t ws_size,
                              hipStream_t stream) {
    const float* feats   = (const float*)d_in[0];
    const float* in_pos  = (const float*)d_in[1];
    const float* out_pos = (const float*)d_in[2];
    const float* extents = (const float*)d_in[3];
    const float* kmat    = (const float*)d_in[4];
    const float* bias    = (const float*)d_in[5];
    const int*   nidx    = (const int*)d_in[6];
    const int*   rsplits = (const int*)d_in[7];
    const int n_out   = in_sizes[7] - 1;
    const int n_edges = in_sizes[6];
    const int ntiles  = (n_out + 15) >> 4;
    const int grid    = (ntiles + TPB - 1) / TPB;

    sphconv_esplit<<<grid, BLOCK, 0, stream>>>(
        feats, in_pos, out_pos, extents, kmat, bias, nidx, rsplits,
        (float*)d_out, n_out, ntiles, n_edges);
}

// Round 8
// 121.996 us; speedup vs baseline: 1.3414x; 1.1007x over previous
//
#include <hip/hip_runtime.h>

typedef unsigned short u16;
typedef __attribute__((ext_vector_type(8))) short bf16x8;            // MFMA A/B frag
typedef __attribute__((ext_vector_type(8))) unsigned short u16x8;    // 8 bf16 = 16B
typedef __attribute__((ext_vector_type(4))) float f32x4;             // MFMA C/D frag

#define WPB   4              // waves per block; one 16-output tile per wave
#define BLOCK (WPB * 64)

__device__ __forceinline__ float bf2f(u16 u) {
    union { unsigned i; float f; } v; v.i = (unsigned)u << 16; return v.f;
}
__device__ __forceinline__ u16 f2bf(float f) {   // RNE f32 -> bf16
    union { float f; unsigned u; } v; v.f = f;
    unsigned r = v.u + 0x7fff + ((v.u >> 16) & 1);
    return (u16)(r >> 16);
}

// prep: feats f32 [N_IN*64] -> bf16 rows in d_ws (halves A2 gather traffic)
__global__ __launch_bounds__(256)
void prep_feats(const float* __restrict__ feats, u16* __restrict__ fbf, int n8) {
    const int id = blockIdx.x * 256 + threadIdx.x;
    if (id < n8) {
        const float4 a = ((const float4*)feats)[2 * id];
        const float4 b = ((const float4*)feats)[2 * id + 1];
        union { u16 h[8]; int4 v; } p;
        p.h[0] = f2bf(a.x); p.h[1] = f2bf(a.y); p.h[2] = f2bf(a.z); p.h[3] = f2bf(a.w);
        p.h[4] = f2bf(b.x); p.h[5] = f2bf(b.y); p.h[6] = f2bf(b.z); p.h[7] = f2bf(b.w);
        ((int4*)fbf)[id] = p.v;
    }
}

// R3 structure exactly; only the A2 feat gather dtype differs (WS: bf16 from d_ws).
//   A1: 256 edges spread over lanes (4/lane) -> sph[4] + idx staged in LDS
//   A2: lane(m=lane&15, quad) accumulates acc[kstep][j] (A-frag layout), unroll 4
//   B : 4 n-tiles x 8 k-steps of mfma_f32_16x16x32_bf16 vs LDS B-frags
template<bool WS>
__global__ __launch_bounds__(BLOCK, 3)
void sphconv_mfma(const float* __restrict__ featsf,   // [N_IN, 64] f32
                  const u16* __restrict__ fbf,        // [N_IN, 64] bf16 (d_ws)
                  const float* __restrict__ in_pos,   // [N_IN, 3]
                  const float* __restrict__ out_pos,  // [N_OUT, 3]
                  const float* __restrict__ extents,  // [1]
                  const float* __restrict__ kmat,     // [4,64,64] = [k=256][f=64]
                  const float* __restrict__ bias,     // [64]
                  const int* __restrict__ nidx,       // [E]
                  const int* __restrict__ rsplits,    // [N_OUT+1]
                  float* __restrict__ out,            // [N_OUT,64]
                  int n_out, int ntiles)
{
    __shared__ u16 KB[4 * 8 * 64 * 8];       // 32 KB: [nt][ks][lane][j] B-frags
    __shared__ int   idxL[WPB][16][16];      // [wave][t][m]       (4 KB)
    __shared__ float sphL[WPB][16][16][4];   // [wave][t][m][s]    (16 KB)

    const int tid  = threadIdx.x;
    const int wave = tid >> 6;
    const int lane = tid & 63;

    // ---- stage K (broadcast f32 read -> bf16 B-fragments; once) ----
    for (int i = tid; i < 16384; i += BLOCK) {
        const int n = i & 63, k = i >> 6;               // kmat flat = [k][n]
        const int kstep = k >> 5, quad = (k >> 3) & 3, j = k & 7;
        const int ntile = n >> 4, lanep = (quad << 4) | (n & 15);
        KB[((((ntile << 3) | kstep) << 6) | lanep) * 8 + j] = f2bf(kmat[i]);
    }
    __syncthreads();   // the only block-wide barrier

    const int tile = blockIdx.x * WPB + wave;
    if (tile >= ntiles) return;

    const float inv_ext = __fdividef(1.0f, extents[0]);

    // ---------------- Phase A1: per-edge spherical basis (4 edges/lane) ----------------
    #pragma unroll
    for (int u = 0; u < 4; ++u) {
        const int slot = (u << 6) | lane;      // 0..255 within tile
        const int m = slot >> 4, t = slot & 15;
        const int o = (tile << 4) | m;
        float rn = 0.f, cph = 0.f, sth = 0.f, cth = 0.f;
        int idx = 0;
        if (o < n_out) {
            const int e0 = rsplits[o], e1 = rsplits[o + 1];
            const int e = e0 + t;
            if (e < e1) {
                idx = nidx[e];
                const float dx = in_pos[idx * 3 + 0] - out_pos[o * 3 + 0];
                const float dy = in_pos[idx * 3 + 1] - out_pos[o * 3 + 1];
                const float dz = in_pos[idx * 3 + 2] - out_pos[o * 3 + 2];
                const float rp2 = dx * dx + dy * dy;
                const float r2  = rp2 + dz * dz;
                const float rs  = fmaxf(sqrtf(r2), 1e-10f);
                const float rp  = fmaxf(sqrtf(rp2), 1e-10f);
                const float ir  = __fdividef(1.0f, rs);
                const float irp = __fdividef(1.0f, rp);
                rn  = rs * inv_ext;
                cph = dz * ir;
                sth = dy * irp;
                cth = dx * irp;
            }
        }
        idxL[wave][t][m] = idx;
        f32x4 sv; sv.x = rn; sv.y = cph; sv.z = sth; sv.w = cth;
        *(f32x4*)&sphL[wave][t][m][0] = sv;     // ds_write_b128
    }
    __builtin_amdgcn_wave_barrier();   // order A1 LDS writes vs A2 cross-lane reads

    // ---------------- Phase A2: accumulate A-fragments in registers ----------------
    const int m    = lane & 15;
    const int quad = lane >> 4;
    float acc[8][8];
    #pragma unroll
    for (int ks = 0; ks < 8; ++ks)
        #pragma unroll
        for (int j = 0; j < 8; ++j) acc[ks][j] = 0.f;

    #pragma unroll 4
    for (int t = 0; t < 16; ++t) {
        const int   idx = idxL[wave][t][m];
        const f32x4 sv  = *(const f32x4*)&sphL[wave][t][m][0];
        float lo[8], hi[8];
        if constexpr (WS) {
            const u16x8 f0 = *(const u16x8*)(fbf + (idx << 6) + (quad << 3));       // 16B
            const u16x8 f1 = *(const u16x8*)(fbf + (idx << 6) + 32 + (quad << 3));  // 16B
            #pragma unroll
            for (int j = 0; j < 8; ++j) { lo[j] = bf2f(f0[j]); hi[j] = bf2f(f1[j]); }
        } else {
            const float* fr = featsf + (idx << 6) + (quad << 3);
            const float4 lo0 = *(const float4*)(fr +  0);
            const float4 lo1 = *(const float4*)(fr +  4);
            const float4 hi0 = *(const float4*)(fr + 32);
            const float4 hi1 = *(const float4*)(fr + 36);
            lo[0] = lo0.x; lo[1] = lo0.y; lo[2] = lo0.z; lo[3] = lo0.w;
            lo[4] = lo1.x; lo[5] = lo1.y; lo[6] = lo1.z; lo[7] = lo1.w;
            hi[0] = hi0.x; hi[1] = hi0.y; hi[2] = hi0.z; hi[3] = hi0.w;
            hi[4] = hi1.x; hi[5] = hi1.y; hi[6] = hi1.z; hi[7] = hi1.w;
        }
        #pragma unroll
        for (int s = 0; s < 4; ++s) {
            const float w = sv[s];
            float* aL = acc[2 * s];          // c = quad*8 + j
            float* aH = acc[2 * s + 1];      // c = 32 + quad*8 + j
            #pragma unroll
            for (int j = 0; j < 8; ++j) {
                aL[j] = fmaf(w, lo[j], aL[j]);
                aH[j] = fmaf(w, hi[j], aH[j]);
            }
        }
    }

    // ---- pack acc -> bf16 A-fragments ----
    bf16x8 afr[8];
    #pragma unroll
    for (int ks = 0; ks < 8; ++ks) {
        union { u16 h[8]; bf16x8 v; } p;
        #pragma unroll
        for (int j = 0; j < 8; ++j) p.h[j] = f2bf(acc[ks][j]);
        afr[ks] = p.v;
    }

    // ---------------- Phase B: 4 n-tiles x 8 k-steps of MFMA ----------------
    const int obase = tile << 4;
    #pragma unroll
    for (int nt = 0; nt < 4; ++nt) {
        f32x4 C = {0.f, 0.f, 0.f, 0.f};
        const u16* kb = &KB[((nt << 3) << 6) * 8 + lane * 8];
        #pragma unroll
        for (int ks = 0; ks < 8; ++ks) {
            const bf16x8 b = *(const bf16x8*)(kb + (ks << 6) * 8);  // ds_read_b128
            C = __builtin_amdgcn_mfma_f32_16x16x32_bf16(afr[ks], b, C, 0, 0, 0);
        }
        const int f  = (nt << 4) | m;          // n = lane&15
        const float bv = bias[f];
        #pragma unroll
        for (int r = 0; r < 4; ++r) {
            const int oo = obase + (quad << 2) + r;   // m = quad*4 + reg
            if (oo < n_out) out[(oo << 6) | f] = C[r] + bv;
        }
    }
}

extern "C" void kernel_launch(void* const* d_in, const int* in_sizes, int n_in,
                              void* d_out, int out_size, void* d_ws, size_t ws_size,
                              hipStream_t stream) {
    const float* feats   = (const float*)d_in[0];
    const float* in_pos  = (const float*)d_in[1];
    const float* out_pos = (const float*)d_in[2];
    const float* extents = (const float*)d_in[3];
    const float* kmat    = (const float*)d_in[4];
    const float* bias    = (const float*)d_in[5];
    const int*   nidx    = (const int*)d_in[6];
    const int*   rsplits = (const int*)d_in[7];
    const int n_out  = in_sizes[7] - 1;
    const int ntiles = (n_out + 15) >> 4;
    const int grid   = (ntiles + WPB - 1) / WPB;

    const size_t fbf_bytes = (size_t)in_sizes[0] * 2;
    if (ws_size >= fbf_bytes && (in_sizes[0] & 7) == 0) {
        u16* fbf = (u16*)d_ws;
        const int n8 = in_sizes[0] / 8;
        prep_feats<<<(n8 + 255) / 256, 256, 0, stream>>>(feats, fbf, n8);
        sphconv_mfma<true><<<grid, BLOCK, 0, stream>>>(
            feats, fbf, in_pos, out_pos, extents, kmat, bias, nidx, rsplits,
            (float*)d_out, n_out, ntiles);
    } else {
        sphconv_mfma<false><<<grid, BLOCK, 0, stream>>>(
            feats, nullptr, in_pos, out_pos, extents, kmat, bias, nidx, rsplits,
            (float*)d_out, n_out, ntiles);
    }
}

// Round 9
// 115.323 us; speedup vs baseline: 1.4191x; 1.0579x over previous
//
#include <hip/hip_runtime.h>

typedef unsigned short u16;
typedef __attribute__((ext_vector_type(8))) short bf16x8;            // MFMA A/B frag
typedef __attribute__((ext_vector_type(8))) unsigned short u16x8;    // 8 bf16 = 16B
typedef __attribute__((ext_vector_type(4))) float f32x4;             // MFMA C/D frag

#define TPS   4                  // tile slots per block
#define BLOCK (TPS * 2 * 64)     // 512: 2 k-half waves per tile

__device__ __forceinline__ float bf2f(u16 u) {
    union { unsigned i; float f; } v; v.i = (unsigned)u << 16; return v.f;
}
__device__ __forceinline__ u16 f2bf(float f) {   // RNE f32 -> bf16
    union { float f; unsigned u; } v; v.f = f;
    unsigned r = v.u + 0x7fff + ((v.u >> 16) & 1);
    return (u16)(r >> 16);
}

// prep: feats f32 [N_IN*64] -> bf16 rows in d_ws (halves gather traffic; R8 win)
__global__ __launch_bounds__(256)
void prep_feats(const float* __restrict__ feats, u16* __restrict__ fbf, int n8) {
    const int id = blockIdx.x * 256 + threadIdx.x;
    if (id < n8) {
        const float4 a = ((const float4*)feats)[2 * id];
        const float4 b = ((const float4*)feats)[2 * id + 1];
        union { u16 h[8]; int4 v; } p;
        p.h[0] = f2bf(a.x); p.h[1] = f2bf(a.y); p.h[2] = f2bf(a.z); p.h[3] = f2bf(a.w);
        p.h[4] = f2bf(b.x); p.h[5] = f2bf(b.y); p.h[6] = f2bf(b.z); p.h[7] = f2bf(b.w);
        ((int4*)fbf)[id] = p.v;
    }
}

// R9: one tile (16 outputs) = TWO waves (k-halves kh=0/1). Wave kh gathers only
// c = kh*32 + [0,32) of each neighbor row (16B/lane/t) and computes k-steps
// ks = 2s+kh; partial C summed via LDS. sph/idx shared per tile.
//   A1 (split over both waves): slot=(m<<4)|t -> coalesced nidx; sph f16 -> LDS [t][m]
//   A2: lane(m=lane&15, quad) acc[s][j] += sph_t[s]*feat[idx_t][kh*32+quad*8+j]
//   B : 4 nt x 4 ks mfma_f32_16x16x32_bf16 vs LDS B-frags -> partial C
//   Red: kh=1 writes C in 2 chunks (aliases sphT); kh=0 sums + bias + stores.
template<bool WS>
__global__ __launch_bounds__(BLOCK)
void sphconv_ksplit(const float* __restrict__ featsf,   // [N_IN, 64] f32
                    const u16* __restrict__ fbf,        // [N_IN, 64] bf16 (d_ws)
                    const float* __restrict__ in_pos,   // [N_IN, 3]
                    const float* __restrict__ out_pos,  // [N_OUT, 3]
                    const float* __restrict__ extents,  // [1]
                    const float* __restrict__ kmat,     // [4,64,64] = [k=256][f=64]
                    const float* __restrict__ bias,     // [64]
                    const int* __restrict__ nidx,       // [E]
                    const int* __restrict__ rsplits,    // [N_OUT+1]
                    float* __restrict__ out,            // [N_OUT,64]
                    int n_out, int ntiles, int n_edges)
{
    __shared__ u16 KB[16384];                     // 32 KB: [nt][ks][lane][j] B-frags
    __shared__ int idxT[TPS][16][16];             // [ts][t][m]          4 KB
    __shared__ _Float16 sphT[TPS][16][16][4];     // [ts][t][m][s]       8 KB (red alias)

    const int tid = threadIdx.x, wave = tid >> 6, lane = tid & 63;
    const int ts = wave >> 1;                     // tile slot
    const int kh = wave & 1;                      // k-half (c-half)

    // ---- stage K as bf16 MFMA B-fragments (proven R3 formula) ----
    for (int i = tid; i < 16384; i += BLOCK) {
        const int n = i & 63, k = i >> 6;         // kmat flat = [k][n]
        const int kstep = k >> 5, quad = (k >> 3) & 3, j = k & 7;
        const int ntile = n >> 4, lanep = (quad << 4) | (n & 15);
        KB[((((ntile << 3) | kstep) << 6) | lanep) * 8 + j] = f2bf(kmat[i]);
    }

    const int tile = blockIdx.x * TPS + ts;
    const int tile_c = min(tile, ntiles - 1);     // clamp: barriers stay uniform
    const int obase = tile_c << 4;
    const int m = lane & 15, quad = lane >> 4;

    const float inv_ext = __fdividef(1.f, extents[0]);

    // ---- A1: tile's 256 (m,t) slots split over the 2 waves, 2 per lane ----
    #pragma unroll
    for (int u = 0; u < 2; ++u) {
        const int slot = (kh << 7) | (u << 6) | lane;   // 0..255, lane-contiguous
        const int mm = slot >> 4, t = slot & 15;
        const int o  = obase + mm;
        const int oc = min(o, n_out - 1);
        const int e0 = rsplits[oc], e1 = rsplits[oc + 1];
        const int e  = e0 + t;
        const bool v = (o < n_out) && (e < e1);
        const int id = nidx[min(e, n_edges - 1)];       // coalesced (e ~ slot)
        const float dx = in_pos[id * 3 + 0] - out_pos[oc * 3 + 0];
        const float dy = in_pos[id * 3 + 1] - out_pos[oc * 3 + 1];
        const float dz = in_pos[id * 3 + 2] - out_pos[oc * 3 + 2];
        const float rp2 = dx * dx + dy * dy;
        const float r2  = rp2 + dz * dz;
        const float rs  = fmaxf(sqrtf(r2), 1e-10f);
        const float rp  = fmaxf(sqrtf(rp2), 1e-10f);
        const float ir  = __fdividef(1.f, rs);
        const float irp = __fdividef(1.f, rp);
        union { _Float16 hh[4]; short4 s4; } pk;
        pk.hh[0] = (_Float16)(v ? rs * inv_ext : 0.f);
        pk.hh[1] = (_Float16)(v ? dz * ir      : 0.f);
        pk.hh[2] = (_Float16)(v ? dy * irp     : 0.f);
        pk.hh[3] = (_Float16)(v ? dx * irp     : 0.f);
        idxT[ts][t][mm] = id;                           // [t][m]: A2 conflict-free
        *(short4*)&sphT[ts][t][mm][0] = pk.s4;
    }
    __syncthreads();     // KB + idx/sph staged

    // ---- A2: accumulate this k-half's A-fragments (16B/lane/t gather) ----
    float acc[4][8];
    #pragma unroll
    for (int s = 0; s < 4; ++s)
        #pragma unroll
        for (int j = 0; j < 8; ++j) acc[s][j] = 0.f;

    #pragma unroll 4
    for (int t = 0; t < 16; ++t) {
        const int idx = idxT[ts][t][m];                          // broadcast x4 quads
        union { short4 s4; _Float16 hh[4]; } up;
        up.s4 = *(const short4*)&sphT[ts][t][m][0];
        float fv[8];
        if constexpr (WS) {
            const u16x8 f0 = *(const u16x8*)(fbf + (idx << 6) + (kh << 5) + (quad << 3));
            #pragma unroll
            for (int j = 0; j < 8; ++j) fv[j] = bf2f(f0[j]);
        } else {
            const float* fr = featsf + (idx << 6) + (kh << 5) + (quad << 3);
            const float4 a0 = *(const float4*)fr;
            const float4 a1 = *(const float4*)(fr + 4);
            fv[0] = a0.x; fv[1] = a0.y; fv[2] = a0.z; fv[3] = a0.w;
            fv[4] = a1.x; fv[5] = a1.y; fv[6] = a1.z; fv[7] = a1.w;
        }
        #pragma unroll
        for (int s = 0; s < 4; ++s) {
            const float w = (float)up.hh[s];
            #pragma unroll
            for (int j = 0; j < 8; ++j)
                acc[s][j] = fmaf(w, fv[j], acc[s][j]);
        }
    }

    // ---- pack -> bf16 A-frags; 4 nt x 4 ks MFMA (ks = 2s+kh) ----
    bf16x8 afr[4];
    #pragma unroll
    for (int s = 0; s < 4; ++s) {
        union { u16 hh[8]; bf16x8 v; } p;
        #pragma unroll
        for (int j = 0; j < 8; ++j) p.hh[j] = f2bf(acc[s][j]);
        afr[s] = p.v;
    }

    f32x4 C[4] = {{0,0,0,0},{0,0,0,0},{0,0,0,0},{0,0,0,0}};
    const bf16x8* kbp = (const bf16x8*)KB;
    #pragma unroll
    for (int nt = 0; nt < 4; ++nt)
        #pragma unroll
        for (int s = 0; s < 4; ++s) {
            const int ks = (s << 1) | kh;
            const bf16x8 b = kbp[(((nt << 3) | ks) << 6) | lane];
            C[nt] = __builtin_amdgcn_mfma_f32_16x16x32_bf16(afr[s], b, C[nt], 0, 0, 0);
        }

    // ---- pair reduction (red aliases sphT; 2 chunks of 2 nt) + epilogue ----
    f32x4* redp = (f32x4*)sphT;                   // [ts][p][lane] 16B, 8 KB total
    const bool store_ok = (tile < ntiles);
    __syncthreads();                              // all A2 sph reads done
    if (kh == 1) {
        redp[((ts << 1) | 0) * 64 + lane] = C[0];
        redp[((ts << 1) | 1) * 64 + lane] = C[1];
    }
    __syncthreads();
    if (kh == 0 && store_ok) {
        #pragma unroll
        for (int nt = 0; nt < 2; ++nt) {
            const f32x4 P = redp[((ts << 1) | nt) * 64 + lane];
            const int f = (nt << 4) | m;
            const float bv = bias[f];
            #pragma unroll
            for (int r = 0; r < 4; ++r) {
                const int oo = obase + (quad << 2) + r;   // D: m = quad*4 + r
                if (oo < n_out) out[(oo << 6) | f] = C[nt][r] + P[r] + bv;
            }
        }
    }
    __syncthreads();
    if (kh == 1) {
        redp[((ts << 1) | 0) * 64 + lane] = C[2];
        redp[((ts << 1) | 1) * 64 + lane] = C[3];
    }
    __syncthreads();
    if (kh == 0 && store_ok) {
        #pragma unroll
        for (int nt = 2; nt < 4; ++nt) {
            const f32x4 P = redp[((ts << 1) | (nt - 2)) * 64 + lane];
            const int f = (nt << 4) | m;
            const float bv = bias[f];
            #pragma unroll
            for (int r = 0; r < 4; ++r) {
                const int oo = obase + (quad << 2) + r;
                if (oo < n_out) out[(oo << 6) | f] = C[nt][r] + P[r] + bv;
            }
        }
    }
}

extern "C" void kernel_launch(void* const* d_in, const int* in_sizes, int n_in,
                              void* d_out, int out_size, void* d_ws, size_t ws_size,
                              hipStream_t stream) {
    const float* feats   = (const float*)d_in[0];
    const float* in_pos  = (const float*)d_in[1];
    const float* out_pos = (const float*)d_in[2];
    const float* extents = (const float*)d_in[3];
    const float* kmat    = (const float*)d_in[4];
    const float* bias    = (const float*)d_in[5];
    const int*   nidx    = (const int*)d_in[6];
    const int*   rsplits = (const int*)d_in[7];
    const int n_out   = in_sizes[7] - 1;
    const int n_edges = in_sizes[6];
    const int ntiles  = (n_out + 15) >> 4;
    const int grid    = (ntiles + TPS - 1) / TPS;

    const size_t fbf_bytes = (size_t)in_sizes[0] * 2;
    if (ws_size >= fbf_bytes && (in_sizes[0] & 7) == 0) {
        u16* fbf = (u16*)d_ws;
        const int n8 = in_sizes[0] / 8;
        prep_feats<<<(n8 + 255) / 256, 256, 0, stream>>>(feats, fbf, n8);
        sphconv_ksplit<true><<<grid, BLOCK, 0, stream>>>(
            feats, fbf, in_pos, out_pos, extents, kmat, bias, nidx, rsplits,
            (float*)d_out, n_out, ntiles, n_edges);
    } else {
        sphconv_ksplit<false><<<grid, BLOCK, 0, stream>>>(
            feats, nullptr, in_pos, out_pos, extents, kmat, bias, nidx, rsplits,
            (float*)d_out, n_out, ntiles, n_edges);
    }
}